// Round 11
// baseline (114.948 us; speedup 1.0000x reference)
//
#include <hip/hip_runtime.h>
#include <hip/hip_bf16.h>

#define MARGIN 0.0625f

// Problem sizes
#define P 4096             // queries (64*64) = 128 qtiles of 32
#define M 100000           // means
#define MT32 3200          // mean tiles of 32 (3200*32 = 102400 padded)
#define MPAD 102400
#define S 100              // segments (nn grid.x): 32 tiles = 1024 means each
#define TPS 32             // tiles per segment
#define QG 16              // query groups (nn grid.y): 8 qtiles = 256 q/block
#define NQT 128            // total qtiles

using short8 = __attribute__((ext_vector_type(8))) short;
using u4v    = __attribute__((ext_vector_type(4))) unsigned int;
using f16v   = __attribute__((ext_vector_type(16))) float;

// ws layout (bytes):
//   Abuf : 128 qt * 64 lanes * 16 B = 131,072     @ 0
//   Bbuf : 3200 mt * 64 lanes * 16 B = 3,276,800  @ 131,072
//   qq   : 4096 * 4 = 16,384                      @ 3,407,872
//   part : 100 * 4096 * 4 = 1,638,400             @ 3,424,256
#define WS_A_OFF    0
#define WS_B_OFF    131072
#define WS_QQ_OFF   3407872
#define WS_PART_OFF 3424256

__device__ inline unsigned bf16_rn(float x) {
    unsigned u = __float_as_uint(x);
    return (u + 0x7FFFu + ((u >> 16) & 1u)) >> 16;
}
__device__ inline float bf16_tof(unsigned h) { return __uint_as_float(h << 16); }

// ---------------------------------------------------------------------------
// Kernel 1: build 32x32x16-bf16 MFMA fragments.
// K-slot products (u = -2q, v = mean; identical 12-slot split math that gave
// absmax 0.0 in R7-R10):
//   k0..8: 3-term split products for ux*vx, uy*vy, uz*vz
//   k9..11: 1*m1, 1*m2, 1*m3 (3-way |m|^2 split);  k12..15: 0
// Operand layout (generalizes the R7-verified 16x16x32 pattern):
//   row/col = lane&31, k = (lane>>5)*8 + j, dword j>>1, low half = even j.
// ---------------------------------------------------------------------------
__global__ __launch_bounds__(256) void prep_kernel(
    const float* __restrict__ outputs, const float* __restrict__ c2ws,
    const float* __restrict__ scales,  const float* __restrict__ means,
    u4v* __restrict__ Abuf, u4v* __restrict__ Bbuf,
    float* __restrict__ qq, float* __restrict__ out)
{
    int idx = blockIdx.x * 256 + threadIdx.x;
    if (idx == 0) out[0] = 0.0f;   // reduce atomicAdds later (stream-ordered)

    if (idx < MPAD) {              // ---- mean side ----
        float x = 0.0f, y = 0.0f, z = 0.0f, mm = 1e30f;  // pad: never wins min
        if (idx < M) {
            x = means[3 * idx]; y = means[3 * idx + 1]; z = means[3 * idx + 2];
            mm = fmaf(x, x, fmaf(y, y, z * z));
        }
        unsigned xh = bf16_rn(x), yh = bf16_rn(y), zh = bf16_rn(z);
        unsigned xl = bf16_rn(x - bf16_tof(xh));
        unsigned yl = bf16_rn(y - bf16_tof(yh));
        unsigned zl = bf16_rn(z - bf16_tof(zh));
        unsigned m1 = bf16_rn(mm);
        float   r1 = mm - bf16_tof(m1);
        unsigned m2 = bf16_rn(r1);
        unsigned m3 = bf16_rn(r1 - bf16_tof(m2));

        int mt = idx >> 5, n = idx & 31;
        u4v* dst = Bbuf + mt * 64 + n;
        // half 0: k0..7 = [vxh vxl vxh vyh vyl vyh vzh vzl]
        dst[0]  = (u4v){xh | (xl << 16), xh | (yh << 16),
                        yl | (yh << 16), zh | (zl << 16)};
        // half 1: k8..15 = [vzh m1 m2 m3 0 0 0 0]
        dst[32] = (u4v){zh | (m1 << 16), m2 | (m3 << 16), 0u, 0u};
        return;
    }

    int qidx = idx - MPAD;         // ---- query side ----
    if (qidx < P) {
        int b = qidx >> 6;
        float s  = scales[b];
        float o0 = outputs[3 * qidx + 0];
        float o1 = outputs[3 * qidx + 1];
        float o2 = outputs[3 * qidx + 2];
        const float* cw = c2ws + b * 16;
        float q0 = fmaf(s, fmaf(cw[0],  o0, fmaf(cw[1],  o1, cw[2]  * o2)), cw[3]);
        float q1 = fmaf(s, fmaf(cw[4],  o0, fmaf(cw[5],  o1, cw[6]  * o2)), cw[7]);
        float q2 = fmaf(s, fmaf(cw[8],  o0, fmaf(cw[9],  o1, cw[10] * o2)), cw[11]);
        qq[qidx] = fmaf(q0, q0, fmaf(q1, q1, q2 * q2));
        float ux = -2.0f * q0, uy = -2.0f * q1, uz = -2.0f * q2;
        unsigned xh = bf16_rn(ux), yh = bf16_rn(uy), zh = bf16_rn(uz);
        unsigned xl = bf16_rn(ux - bf16_tof(xh));
        unsigned yl = bf16_rn(uy - bf16_tof(yh));
        unsigned zl = bf16_rn(uz - bf16_tof(zh));
        const unsigned ONE = 0x3F80u;   // bf16 1.0

        int qt = qidx >> 5, m = qidx & 31;
        u4v* dst = Abuf + qt * 64 + m;
        // half 0: k0..7 = [uxh uxh uxl uyh uyh uyl uzh uzh]
        dst[0]  = (u4v){xh | (xh << 16), xl | (yh << 16),
                        yh | (yl << 16), zh | (zh << 16)};
        // half 1: k8..15 = [uzl 1 1 1 0 0 0 0]
        dst[32] = (u4v){zl | (ONE << 16), ONE | (ONE << 16), 0u, 0u};
    }
}

// ---------------------------------------------------------------------------
// Kernel 2: MFMA NN scan, 32x32x16 bf16 (1024 pairs/MFMA, 4x the 16x16
// shapes -- amortizes whatever per-MFMA overhead plagued R7-R10).
// Grid (S=100, QG=16) = 1600 blocks x 4 waves. Block: stage segment's 32 KB
// of B into LDS once, barrier; wave holds 2 qtile A-frags + 2 f16v running
// mins; 16 rounds x (2 LDS B-frags prefetched 1 round ahead, 4 MFMA,
// 32 v_min3). Epilogue: 5-level xor-shuffle col-min, 2 lanes store rows.
// C/D layout: col=lane&31, row=(reg&3)+8*(reg>>2)+4*(lane>>5) [m74/m101].
// ---------------------------------------------------------------------------
__global__ __launch_bounds__(256, 4) void nn_kernel(
    const short8* __restrict__ Abuf, const short8* __restrict__ Bbuf,
    float* __restrict__ partial)     // [S][P]
{
    const int t = threadIdx.x, lane = t & 63, wave = t >> 6;
    const int s  = blockIdx.x;
    const int qg = blockIdx.y;
    const int qt0 = qg * 8 + wave * 2;

    __shared__ short8 ldsB[TPS * 64];   // 32 KB

    const short8* src = Bbuf + (size_t)s * (TPS * 64);
#pragma unroll
    for (int k = 0; k < 8; ++k)
        ldsB[t + k * 256] = src[t + k * 256];

    short8 a0 = Abuf[qt0 * 64 + lane];
    short8 a1 = Abuf[(qt0 + 1) * 64 + lane];
    f16v mn0, mn1, zero;
#pragma unroll
    for (int e = 0; e < 16; ++e) { mn0[e] = 1e30f; mn1[e] = 1e30f; zero[e] = 0.0f; }

    __syncthreads();

    short8 bc0 = ldsB[lane];
    short8 bc1 = ldsB[64 + lane];
#pragma unroll 4
    for (int r = 0; r < TPS / 2; ++r) {
        int nr = (r + 1) & (TPS / 2 - 1);          // wrap: last prefetch benign
        short8 bn0 = ldsB[(nr * 2) * 64 + lane];
        short8 bn1 = ldsB[(nr * 2 + 1) * 64 + lane];
        f16v c0 = __builtin_amdgcn_mfma_f32_32x32x16_bf16(a0, bc0, zero, 0, 0, 0);
        f16v c1 = __builtin_amdgcn_mfma_f32_32x32x16_bf16(a0, bc1, zero, 0, 0, 0);
        mn0 = __builtin_elementwise_min(mn0, __builtin_elementwise_min(c0, c1));
        f16v d0 = __builtin_amdgcn_mfma_f32_32x32x16_bf16(a1, bc0, zero, 0, 0, 0);
        f16v d1 = __builtin_amdgcn_mfma_f32_32x32x16_bf16(a1, bc1, zero, 0, 0, 0);
        mn1 = __builtin_elementwise_min(mn1, __builtin_elementwise_min(d0, d1));
        bc0 = bn0; bc1 = bn1;
    }

    // col-min across the 32 lanes of each half (masks stay within a half)
#pragma unroll
    for (int msk = 1; msk < 32; msk <<= 1) {
        f16v o0, o1;
#pragma unroll
        for (int e = 0; e < 16; ++e) {
            o0[e] = __shfl_xor(mn0[e], msk, 64);
            o1[e] = __shfl_xor(mn1[e], msk, 64);
        }
        mn0 = __builtin_elementwise_min(mn0, o0);
        mn1 = __builtin_elementwise_min(mn1, o1);
    }

    if ((lane & 31) == 0) {
        const int half = lane >> 5;
        float* dst = partial + (size_t)s * P;
#pragma unroll
        for (int r = 0; r < 16; ++r) {
            int row = (r & 3) + 8 * (r >> 2) + 4 * half;
            dst[qt0 * 32 + row]       = mn0[r];
            dst[(qt0 + 1) * 32 + row] = mn1[r];
        }
    }
}

// ---------------------------------------------------------------------------
// Kernel 3: final reduce. 16 blocks x 256 thr; thread q: min over S=100
// segments (coalesced, L2-hot 1.6 MB), d2 = clamp(qq+min,0),
// relu(MARGIN-d2)/P, wave+LDS sum, atomicAdd into out.
// ---------------------------------------------------------------------------
__global__ __launch_bounds__(256) void reduce_kernel(
    const float* __restrict__ partial, const float* __restrict__ qq,
    float* __restrict__ out)
{
    const int t = threadIdx.x;
    const int q = blockIdx.x * 256 + t;

    float m = 1e30f;
#pragma unroll 4
    for (int s = 0; s < S; ++s)
        m = fminf(m, partial[s * P + q]);

    float d2 = fmaxf(qq[q] + m, 0.0f);
    float v = fmaxf(MARGIN - d2, 0.0f) * (1.0f / (float)P);

#pragma unroll
    for (int off = 32; off > 0; off >>= 1)
        v += __shfl_down(v, off, 64);

    __shared__ float lds[4];
    int wid = t >> 6;
    if ((t & 63) == 0) lds[wid] = v;
    __syncthreads();
    if (t == 0)
        atomicAdd(out, lds[0] + lds[1] + lds[2] + lds[3]);
}

extern "C" void kernel_launch(void* const* d_in, const int* in_sizes, int n_in,
                              void* d_out, int out_size, void* d_ws, size_t ws_size,
                              hipStream_t stream) {
    const float* outputs = (const float*)d_in[0];  // (64,64,3)
    const float* c2ws    = (const float*)d_in[1];  // (64,4,4)
    const float* scales  = (const float*)d_in[2];  // (64,)
    const float* means   = (const float*)d_in[3];  // (100000,3)

    char* ws = (char*)d_ws;
    u4v*   AbufW   = (u4v*)(ws + WS_A_OFF);
    u4v*   BbufW   = (u4v*)(ws + WS_B_OFF);
    float* qq      = (float*)(ws + WS_QQ_OFF);
    float* partial = (float*)(ws + WS_PART_OFF);
    float* out     = (float*)d_out;

    prep_kernel<<<(MPAD + P) / 256, 256, 0, stream>>>(
        outputs, c2ws, scales, means, AbufW, BbufW, qq, out);
    nn_kernel<<<dim3(S, QG), 256, 0, stream>>>(
        (const short8*)AbufW, (const short8*)BbufW, partial);
    reduce_kernel<<<16, 256, 0, stream>>>(partial, qq, out);
}